// Round 6
// baseline (1121.062 us; speedup 1.0000x reference)
//
#include <hip/hip_runtime.h>

// Decoder_75720273428908 — transformerCPI decoder, round 10.
// B=16, T=512, S=1024, H=256, NH=8, D=32, PF=512, L=2, A=64.
// Round-10: dispatch-chain fusion (rounds 8-9 kernel speedups moved total
// <75us combined -> serial launch chain is the bottleneck).
//  - gemm_oln: o-proj/FFN2 GEMM + residual + LayerNorm + bf16-split in ONE
//    kernel (BM=64 x BN=256 full-row blocks; two-pass LN, shuffle+LDS reduce).
//    Removes 6 residual_ln launches + sub buffer (96MB traffic).
//  - gemm_eakv: EA K/V for BOTH layers in one upfront launch (src-only dep).
//  - pool2+fc_head merged. Launches 29 -> 23.
// Out layout (fp32 elems): label[32] @0, pooled[4096] @32, att[67108864] @4128.
//
// WS layout (MB): x@0(8) x_hi@8(4) x_lo@12(4) qbh@16(4) qbl@20(4) sakh@24(4)
//  sakl@28(4) savth@32(4) savtl@36(4) obh@40(4) obl@44(4) srch@48(8) srcl@56(8)
//  eak0@64(16) eav0t@80(16) eak1@96(16) eav1t@112(16) ffm@128(16) w@144(8).
//  Aliases: trg split->ffm (pre-loop); nrm/part->qbh (post-loop). Total 152MB.

typedef __bf16 bfrag __attribute__((ext_vector_type(8)));
typedef float f32x4 __attribute__((ext_vector_type(4)));
typedef unsigned int uint4v __attribute__((ext_vector_type(4)));

// ---------------- bf16 split helpers --------------------------------------
__device__ __forceinline__ unsigned short f2bf(float x) {
  unsigned u = __float_as_uint(x);
  u += 0x7fff + ((u >> 16) & 1);            // RNE
  return (unsigned short)(u >> 16);
}
__device__ __forceinline__ float bf2f(unsigned short h) {
  return __uint_as_float((unsigned)h << 16);
}
__device__ __forceinline__ void split2(float x, unsigned short& hi, unsigned short& lo) {
  hi = f2bf(x);
  lo = f2bf(x - bf2f(hi));                  // residual exact in fp32
}

// ---------------- async global->LDS 16B -----------------------------------
__device__ __forceinline__ void load16_lds(const short* g, short* l) {
  __builtin_amdgcn_global_load_lds(
      (const __attribute__((address_space(1))) unsigned int*)g,
      (__attribute__((address_space(3))) unsigned int*)l, 16, 0, 0);
}

// ---------------- fused weight transpose+split (all weights, one launch) ---
struct WDesc { const float* src; long long dst; int K; int N; int tile0; int pad; };
struct WAll { WDesc d[21]; };

__global__ __launch_bounds__(256) void wsplit_all(
    WAll P, short* __restrict__ Th, short* __restrict__ Tl)
{
  __shared__ float t[32][33];
  const int bid = blockIdx.x;
  int i = 0;
  while (i < 20 && bid >= P.d[i + 1].tile0) i++;   // uniform per block
  const float* __restrict__ W = P.d[i].src;
  const int K = P.d[i].K, N = P.d[i].N;
  const int lt = bid - P.d[i].tile0;
  const int ntn = N >> 5;
  const int n0 = (lt % ntn) * 32, k0 = (lt / ntn) * 32;
  short* th = Th + P.d[i].dst;
  short* tl = Tl + P.d[i].dst;
  const int tx = threadIdx.x & 31, ty = threadIdx.x >> 5;
#pragma unroll
  for (int p = 0; p < 4; p++)
    t[ty + p * 8][tx] = W[(size_t)(k0 + ty + p * 8) * N + n0 + tx];
  __syncthreads();
#pragma unroll
  for (int p = 0; p < 4; p++) {
    float v = t[tx][ty + p * 8];            // k=k0+tx, n=n0+ty+p*8
    unsigned short hi, lo; split2(v, hi, lo);
    size_t o = (size_t)(n0 + ty + p * 8) * K + k0 + tx;
    th[o] = (short)hi; tl[o] = (short)lo;
  }
}

// ---------------- flat split: X fp32 -> Xh,Xl bf16 -------------------------
__global__ __launch_bounds__(256) void xsplit(
    const float* __restrict__ X, short* __restrict__ Xh, short* __restrict__ Xl,
    int n4)
{
  int i = blockIdx.x * 256 + threadIdx.x;
  if (i < n4) {
    float4 v = ((const float4*)X)[i];
    ushort4 h, l;
    split2(v.x, h.x, l.x); split2(v.y, h.y, l.y);
    split2(v.z, h.z, l.z); split2(v.w, h.w, l.w);
    ((ushort4*)Xh)[i] = h; ((ushort4*)Xl)[i] = l;
  }
}

// ---------------- GEMM core: 128x128 tile, BK=32, gload_lds staging -------
#define GEMM128_CORE(Ah_g, Al_g, Bh_g, Bl_g, K)                                \
  for (int k0 = 0; k0 < K; k0 += 32) {                                         \
    _Pragma("unroll")                                                          \
    for (int i = 0; i < 2; i++) {                                              \
      const int row = i * 64 + w * 16 + srow;                                  \
      const size_t ga = (size_t)(m0 + row) * K + k0 + sc4 * 8;                 \
      const size_t gb = (size_t)(n0 + row) * K + k0 + sc4 * 8;                 \
      const int ldst = i * 2048 + w * 512;                                     \
      load16_lds(Ah_g + ga, &Asl[0][ldst]);                                    \
      load16_lds(Al_g + ga, &Asl[1][ldst]);                                    \
      load16_lds(Bh_g + gb, &Bsl[0][ldst]);                                    \
      load16_lds(Bl_g + gb, &Bsl[1][ldst]);                                    \
    }                                                                          \
    __syncthreads();                                                           \
    bfrag afh[4], afl[4], bfh[4], bfl[4];                                      \
    _Pragma("unroll")                                                          \
    for (int mi = 0; mi < 4; mi++) {                                           \
      const int r = wm * 64 + mi * 16 + l15;                                   \
      afh[mi] = *(const bfrag*)(&Asl[0][r * 32 + l4 * 8]);                     \
      afl[mi] = *(const bfrag*)(&Asl[1][r * 32 + l4 * 8]);                     \
    }                                                                          \
    _Pragma("unroll")                                                          \
    for (int ni = 0; ni < 4; ni++) {                                           \
      const int r = wn * 64 + ni * 16 + l15;                                   \
      bfh[ni] = *(const bfrag*)(&Bsl[0][r * 32 + l4 * 8]);                     \
      bfl[ni] = *(const bfrag*)(&Bsl[1][r * 32 + l4 * 8]);                     \
    }                                                                          \
    _Pragma("unroll")                                                          \
    for (int mi = 0; mi < 4; mi++)                                             \
      _Pragma("unroll")                                                        \
      for (int ni = 0; ni < 4; ni++) {                                         \
        acc[mi][ni] = __builtin_amdgcn_mfma_f32_16x16x32_bf16(afh[mi], bfh[ni], acc[mi][ni], 0, 0, 0); \
        acc[mi][ni] = __builtin_amdgcn_mfma_f32_16x16x32_bf16(afh[mi], bfl[ni], acc[mi][ni], 0, 0, 0); \
        acc[mi][ni] = __builtin_amdgcn_mfma_f32_16x16x32_bf16(afl[mi], bfh[ni], acc[mi][ni], 0, 0, 0); \
      }                                                                        \
    __syncthreads();                                                           \
  }

// ---------------- plain MFMA GEMM (ft / EA-q / FFN1) ----------------------
template <bool RELU, bool SPLIT, bool WRITE_C>
__global__ __launch_bounds__(256) void gemm_mfma(
    const short* __restrict__ Ah_g, const short* __restrict__ Al_g,
    const short* __restrict__ Bh_g, const short* __restrict__ Bl_g,
    const float* __restrict__ bias, float* __restrict__ C,
    short* __restrict__ Ch, short* __restrict__ Cl,
    int M, int N, int K)
{
  __shared__ short Asl[2][128 * 32];
  __shared__ short Bsl[2][128 * 32];
  const int tid = threadIdx.x;
  const int lane = tid & 63, w = tid >> 6;
  const int wm = w & 1, wn = w >> 1;
  const int m0 = blockIdx.x * 128, n0 = blockIdx.y * 128;
  const int srow = lane >> 2, sc4 = lane & 3;
  const int l15 = lane & 15, l4 = lane >> 4;
  f32x4 acc[4][4] = {};
  GEMM128_CORE(Ah_g, Al_g, Bh_g, Bl_g, K)
#pragma unroll
  for (int mi = 0; mi < 4; mi++)
#pragma unroll
    for (int ni = 0; ni < 4; ni++) {
      const int n = n0 + wn * 64 + ni * 16 + l15;
      const float bv = bias[n];
#pragma unroll
      for (int r = 0; r < 4; r++) {
        const int m = m0 + wm * 64 + mi * 16 + l4 * 4 + r;
        float v = acc[mi][ni][r] + bv;
        if (RELU) v = fmaxf(v, 0.f);
        const size_t o = (size_t)m * N + n;
        if constexpr (WRITE_C) C[o] = v;
        if constexpr (SPLIT) {
          unsigned short hh, ll; split2(v, hh, ll);
          Ch[o] = (short)hh; Cl[o] = (short)ll;
        }
      }
    }
}

// ---------------- fused SA QKV projection GEMM ----------------------------
// B^T rows: 3 consecutive [256,K] weight blocks (q,k,v). seg = n0>>8.
// seg 2 (V) -> V^T layout [b][h][d][1<<tksh]; others -> split bf16 [M,256].
__global__ __launch_bounds__(256) void gemm_qkv(
    const short* __restrict__ Ah_g, const short* __restrict__ Al_g,
    const short* __restrict__ Bh_g, const short* __restrict__ Bl_g,
    const float* __restrict__ b0, const float* __restrict__ b1,
    const float* __restrict__ b2,
    short* __restrict__ D0h, short* __restrict__ D0l,
    short* __restrict__ D1h, short* __restrict__ D1l,
    short* __restrict__ D2h, short* __restrict__ D2l,
    int M, int K, int tksh)
{
  __shared__ short Asl[2][128 * 32];
  __shared__ short Bsl[2][128 * 32];
  const int tid = threadIdx.x;
  const int lane = tid & 63, w = tid >> 6;
  const int wm = w & 1, wn = w >> 1;
  const int m0 = blockIdx.x * 128, n0 = blockIdx.y * 128;
  const int srow = lane >> 2, sc4 = lane & 3;
  const int l15 = lane & 15, l4 = lane >> 4;
  f32x4 acc[4][4] = {};
  GEMM128_CORE(Ah_g, Al_g, Bh_g, Bl_g, K)
  const int seg = n0 >> 8;
  const bool vt = (seg == 2);
  const float* bias = (seg == 0) ? b0 : (seg == 1 ? b1 : b2);
  short* Ch = (seg == 0) ? D0h : (seg == 1 ? D1h : D2h);
  short* Cl = (seg == 0) ? D0l : (seg == 1 ? D1l : D2l);
#pragma unroll
  for (int mi = 0; mi < 4; mi++)
#pragma unroll
    for (int ni = 0; ni < 4; ni++) {
      const int n = n0 + wn * 64 + ni * 16 + l15;
      const int nl = n & 255;
      const float bv = bias[nl];
      if (vt) {
        const int m = m0 + wm * 64 + mi * 16 + l4 * 4;
        const int bb = m >> tksh, tt = m & ((1 << tksh) - 1);
        const size_t o = ((((size_t)bb * 8 + (nl >> 5)) * 32 + (nl & 31)) << tksh) + tt;
        unsigned long long wh = 0, wl = 0;
#pragma unroll
        for (int r = 0; r < 4; r++) {
          float v = acc[mi][ni][r] + bv;
          unsigned short hh, ll; split2(v, hh, ll);
          wh |= (unsigned long long)hh << (16 * r);
          wl |= (unsigned long long)ll << (16 * r);
        }
        *(unsigned long long*)(Ch + o) = wh;
        *(unsigned long long*)(Cl + o) = wl;
      } else {
#pragma unroll
        for (int r = 0; r < 4; r++) {
          const int m = m0 + wm * 64 + mi * 16 + l4 * 4 + r;
          float v = acc[mi][ni][r] + bv;
          unsigned short hh, ll; split2(v, hh, ll);
          const size_t o = (size_t)m * 256 + nl;
          Ch[o] = (short)hh; Cl[o] = (short)ll;
        }
      }
    }
}

// ---------------- EA K/V for both layers, one launch ----------------------
// B^T rows: [l0 wk | l0 wv | l1 wk | l1 wv] (4 x 256). seg = n0>>8:
// kv = seg&1 (1 -> V^T tksh=10), layer = seg>>1. M = 16384 (src rows).
__global__ __launch_bounds__(256) void gemm_eakv(
    const short* __restrict__ Ah_g, const short* __restrict__ Al_g,
    const short* __restrict__ Bh_g, const short* __restrict__ Bl_g,
    const float* __restrict__ bk0, const float* __restrict__ bv0,
    const float* __restrict__ bk1, const float* __restrict__ bv1,
    short* __restrict__ K0h, short* __restrict__ K0l,
    short* __restrict__ V0h, short* __restrict__ V0l,
    short* __restrict__ K1h, short* __restrict__ K1l,
    short* __restrict__ V1h, short* __restrict__ V1l,
    int M, int K)
{
  __shared__ short Asl[2][128 * 32];
  __shared__ short Bsl[2][128 * 32];
  const int tid = threadIdx.x;
  const int lane = tid & 63, w = tid >> 6;
  const int wm = w & 1, wn = w >> 1;
  const int m0 = blockIdx.x * 128, n0 = blockIdx.y * 128;
  const int srow = lane >> 2, sc4 = lane & 3;
  const int l15 = lane & 15, l4 = lane >> 4;
  f32x4 acc[4][4] = {};
  GEMM128_CORE(Ah_g, Al_g, Bh_g, Bl_g, K)
  const int seg = n0 >> 8;                  // 0..3
  const bool vt = (seg & 1);
  const float* bias = (seg == 0) ? bk0 : (seg == 1 ? bv0 : (seg == 2 ? bk1 : bv1));
  short* Ch = (seg == 0) ? K0h : (seg == 1 ? V0h : (seg == 2 ? K1h : V1h));
  short* Cl = (seg == 0) ? K0l : (seg == 1 ? V0l : (seg == 2 ? K1l : V1l));
#pragma unroll
  for (int mi = 0; mi < 4; mi++)
#pragma unroll
    for (int ni = 0; ni < 4; ni++) {
      const int n = n0 + wn * 64 + ni * 16 + l15;
      const int nl = n & 255;
      const float bv = bias[nl];
      if (vt) {
        const int m = m0 + wm * 64 + mi * 16 + l4 * 4;
        const int bb = m >> 10, tt = m & 1023;
        const size_t o = ((((size_t)bb * 8 + (nl >> 5)) * 32 + (nl & 31)) << 10) + tt;
        unsigned long long wh = 0, wl = 0;
#pragma unroll
        for (int r = 0; r < 4; r++) {
          float v = acc[mi][ni][r] + bv;
          unsigned short hh, ll; split2(v, hh, ll);
          wh |= (unsigned long long)hh << (16 * r);
          wl |= (unsigned long long)ll << (16 * r);
        }
        *(unsigned long long*)(Ch + o) = wh;
        *(unsigned long long*)(Cl + o) = wl;
      } else {
#pragma unroll
        for (int r = 0; r < 4; r++) {
          const int m = m0 + wm * 64 + mi * 16 + l4 * 4 + r;
          float v = acc[mi][ni][r] + bv;
          unsigned short hh, ll; split2(v, hh, ll);
          const size_t o = (size_t)m * 256 + nl;
          Ch[o] = (short)hh; Cl[o] = (short)ll;
        }
      }
    }
}

// ---------------- GEMM + residual + LayerNorm + split (fused epilogue) ----
// C = A[M,K] @ B^T[256,K] + bias; y = LN(x + C)*g + b; x=y; (xh,xl)=split(y).
// BM=64, BN=256 (full rows per block), 256 threads = 4 waves (1M x 4N).
template <bool WNORM>
__global__ __launch_bounds__(256) void gemm_oln(
    const short* __restrict__ Ah_g, const short* __restrict__ Al_g,
    const short* __restrict__ Bh_g, const short* __restrict__ Bl_g,
    const float* __restrict__ bias, const float* __restrict__ g,
    const float* __restrict__ bi, float* __restrict__ x,
    short* __restrict__ xh, short* __restrict__ xl,
    float* __restrict__ nrm, int K)
{
  __shared__ short Asl[2][64 * 32];
  __shared__ short Bsl[2][256 * 32];
  __shared__ float red[512];                 // [64 rows][4 waves] x2 passes
  const int tid = threadIdx.x;
  const int lane = tid & 63, w = tid >> 6;   // w = N-quadrant (64 cols each)
  const int m0 = blockIdx.x * 64;
  const int l15 = lane & 15, l4 = lane >> 4;
  f32x4 acc[4][4] = {};

  for (int k0 = 0; k0 < K; k0 += 32) {
    {  // A: 64x32 = 256 chunks (1/thread); B: 256x32 = 1024 chunks (4/thread)
      const int arow = tid >> 2, ac4 = tid & 3;
      const size_t ga = (size_t)(m0 + arow) * K + k0 + ac4 * 8;
      load16_lds(Ah_g + ga, &Asl[0][w * 512]);
      load16_lds(Al_g + ga, &Asl[1][w * 512]);
#pragma unroll
      for (int i = 0; i < 4; i++) {
        const int c = i * 256 + tid;
        const int brow = c >> 2, bc4 = c & 3;
        const size_t gb = (size_t)brow * K + k0 + bc4 * 8;
        load16_lds(Bh_g + gb, &Bsl[0][i * 2048 + w * 512]);
        load16_lds(Bl_g + gb, &Bsl[1][i * 2048 + w * 512]);
      }
    }
    __syncthreads();
    bfrag afh[4], afl[4], bfh[4], bfl[4];
#pragma unroll
    for (int mi = 0; mi < 4; mi++) {
      const int r = mi * 16 + l15;
      afh[mi] = *(const bfrag*)(&Asl[0][r * 32 + l4 * 8]);
      afl[mi] = *(const bfrag*)(&Asl[1][r * 32 + l4 * 8]);
    }
#pragma unroll
    for (int ni = 0; ni < 4; ni++) {
      const int c = w * 64 + ni * 16 + l15;
      bfh[ni] = *(const bfrag*)(&Bsl[0][c * 32 + l4 * 8]);
      bfl[ni] = *(const bfrag*)(&Bsl[1][c * 32 + l4 * 8]);
    }
#pragma unroll
    for (int mi = 0; mi < 4; mi++)
#pragma unroll
      for (int ni = 0; ni < 4; ni++) {
        acc[mi][ni] = __builtin_amdgcn_mfma_f32_16x16x32_bf16(afh[mi], bfh[ni], acc[mi][ni], 0, 0, 0);
        acc[mi][ni] = __builtin_amdgcn_mfma_f32_16x16x32_bf16(afh[mi], bfl[ni], acc[mi][ni], 0, 0, 0);
        acc[mi][ni] = __builtin_amdgcn_mfma_f32_16x16x32_bf16(afl[mi], bfh[ni], acc[mi][ni], 0, 0, 0);
      }
    __syncthreads();
  }
  // ---- epilogue: bias + residual; two-pass LN over each 256-wide row ----
  float biasv[4], gv[4], bvv[4];
#pragma unroll
  for (int ni = 0; ni < 4; ni++) {
    const int col = w * 64 + ni * 16 + l15;
    biasv[ni] = bias[col]; gv[ni] = g[col]; bvv[ni] = bi[col];
  }
#pragma unroll
  for (int mi = 0; mi < 4; mi++)
#pragma unroll
    for (int r = 0; r < 4; r++) {
      const size_t row = m0 + mi * 16 + l4 * 4 + r;
#pragma unroll
      for (int ni = 0; ni < 4; ni++)
        acc[mi][ni][r] += biasv[ni] + x[row * 256 + w * 64 + ni * 16 + l15];
    }
  // pass 1: mean
#pragma unroll
  for (int mi = 0; mi < 4; mi++)
#pragma unroll
    for (int r = 0; r < 4; r++) {
      float s = acc[mi][0][r] + acc[mi][1][r] + acc[mi][2][r] + acc[mi][3][r];
#pragma unroll
      for (int off = 1; off < 16; off <<= 1) s += __shfl_xor(s, off, 16);
      if (l15 == 0) red[(mi * 16 + l4 * 4 + r) * 4 + w] = s;
    }
  __syncthreads();
  float mean[4][4];
#pragma unroll
  for (int mi = 0; mi < 4; mi++)
#pragma unroll
    for (int r = 0; r < 4; r++) {
      const int lr = mi * 16 + l4 * 4 + r;
      mean[mi][r] = (red[lr * 4] + red[lr * 4 + 1] + red[lr * 4 + 2] + red[lr * 4 + 3]) * (1.f / 256.f);
    }
  __syncthreads();
  // pass 2: variance
#pragma unroll
  for (int mi = 0; mi < 4; mi++)
#pragma unroll
    for (int r = 0; r < 4; r++) {
      float s2 = 0.f;
#pragma unroll
      for (int ni = 0; ni < 4; ni++) {
        const float d = acc[mi][ni][r] - mean[mi][r];
        s2 += d * d;
      }
#pragma unroll
      for (int off = 1; off < 16; off <<= 1) s2 += __shfl_xor(s2, off, 16);
      if (l15 == 0) red[(mi * 16 + l4 * 4 + r) * 4 + w] = s2;
    }
  __syncthreads();
  float rs[4][4];
#pragma unroll
  for (int mi = 0; mi < 4; mi++)
#pragma unroll
    for (int r = 0; r < 4; r++) {
      const int lr = mi * 16 + l4 * 4 + r;
      const float var = (red[lr * 4] + red[lr * 4 + 1] + red[lr * 4 + 2] + red[lr * 4 + 3]) * (1.f / 256.f);
      rs[mi][r] = rsqrtf(var + 1e-5f);
    }
  if (WNORM) __syncthreads();                // red reused below
  // normalize + write
  float wn2[4][4];
#pragma unroll
  for (int mi = 0; mi < 4; mi++)
#pragma unroll
    for (int r = 0; r < 4; r++) {
      wn2[mi][r] = 0.f;
      const size_t row = m0 + mi * 16 + l4 * 4 + r;
#pragma unroll
      for (int ni = 0; ni < 4; ni++) {
        const int col = w * 64 + ni * 16 + l15;
        const float y = (acc[mi][ni][r] - mean[mi][r]) * rs[mi][r] * gv[ni] + bvv[ni];
        x[row * 256 + col] = y;
        unsigned short hh, ll; split2(y, hh, ll);
        xh[row * 256 + col] = (short)hh;
        xl[row * 256 + col] = (short)ll;
        if (WNORM) wn2[mi][r] += y * y;
      }
    }
  if (WNORM) {
#pragma unroll
    for (int mi = 0; mi < 4; mi++)
#pragma unroll
      for (int r = 0; r < 4; r++) {
        float s2 = wn2[mi][r];
#pragma unroll
        for (int off = 1; off < 16; off <<= 1) s2 += __shfl_xor(s2, off, 16);
        if (l15 == 0) red[(mi * 16 + l4 * 4 + r) * 4 + w] = s2;
      }
    __syncthreads();
    if (w == 0 && l15 == 0) {
#pragma unroll
      for (int mi = 0; mi < 4; mi++)
#pragma unroll
        for (int r = 0; r < 4; r++) {
          const int lr = mi * 16 + l4 * 4 + r;
          nrm[m0 + lr] = sqrtf(red[lr * 4] + red[lr * 4 + 1] + red[lr * 4 + 2] + red[lr * 4 + 3]);
        }
    }
  }
}

// ---------------- MFMA fused attention (512 threads, 8 waves) -------------
template <int TK>
__global__ __launch_bounds__(512, 4) void attn_mfma(
    const short* __restrict__ Qh, const short* __restrict__ Ql,
    const short* __restrict__ Kh, const short* __restrict__ Kl,
    const short* __restrict__ Vth, const short* __restrict__ Vtl,
    short* __restrict__ Oh, short* __restrict__ Ol,
    float* __restrict__ att_out)
{
  __shared__ float sc[16 * TK];                 // 64KB (TK=1024) / 32KB (512)
  const int n = blockIdx.x;
  const int xcd = n & 7, ii = n >> 3;
  const int bh = xcd * 16 + (ii >> 5);          // [0,128)
  const int q0 = (ii & 31) * 16;
  const int b = bh >> 3, h = bh & 7;
  const int tid = threadIdx.x;
  const int lane = tid & 63, w = tid >> 6;      // 8 waves
  const int l15 = lane & 15, l4 = lane >> 4;
  const float inv_scale = 0.17677669529663687f; // 1/sqrt(32)

  const size_t qbase = (((size_t)b * 512 + q0 + l15) * 8 + h) * 32 + l4 * 8;
  bfrag qh = *(const bfrag*)(Qh + qbase);
  bfrag ql = *(const bfrag*)(Ql + qbase);

  // ---- phase 1: S = QK^T/sqrt(D) -----------------------------------------
#pragma unroll
  for (int t = 0; t < TK / 128; t++) {
    const int n0c = w * (TK / 8) + t * 16;
    const size_t kbase = (((size_t)b * TK + n0c + l15) * 8 + h) * 32 + l4 * 8;
    bfrag kh = *(const bfrag*)(Kh + kbase);
    bfrag kl = *(const bfrag*)(Kl + kbase);
    f32x4 acc = {};
    acc = __builtin_amdgcn_mfma_f32_16x16x32_bf16(qh, kh, acc, 0, 0, 0);
    acc = __builtin_amdgcn_mfma_f32_16x16x32_bf16(qh, kl, acc, 0, 0, 0);
    acc = __builtin_amdgcn_mfma_f32_16x16x32_bf16(ql, kh, acc, 0, 0, 0);
    const int col = n0c + l15;
#pragma unroll
    for (int r = 0; r < 4; r++) {
      const int row = l4 * 4 + r;
      sc[row * TK + ((((col >> 2) ^ (row & 7)) << 2) | (col & 3))] = acc[r] * inv_scale;
    }
  }
  __syncthreads();

  // ---- phase 2: softmax stats --------------------------------------------
  const int sr = tid >> 5, sj = tid & 31, srsw = sr & 7;
  float mx = -1e30f;
  for (int k = sj; k < TK; k += 32)
    mx = fmaxf(mx, sc[sr * TK + ((((k >> 2) ^ srsw) << 2) | (k & 3))]);
#pragma unroll
  for (int off = 16; off > 0; off >>= 1) mx = fmaxf(mx, __shfl_xor(mx, off, 32));
  float sum = 0.f;
  for (int k = sj; k < TK; k += 32) {
    const int idx = sr * TK + ((((k >> 2) ^ srsw) << 2) | (k & 3));
    float e = __expf(sc[idx] - mx);
    sc[idx] = e;
    sum += e;
  }
#pragma unroll
  for (int off = 16; off > 0; off >>= 1) sum += __shfl_xor(sum, off, 32);
  const float inv = 1.f / sum;
  __syncthreads();

  // ---- phase 3: att output -----------------------------------------------
  if (att_out) {
    const size_t orow = (((size_t)(b * 8 + h)) * 512 + q0 + sr) * TK;
#pragma unroll
    for (int t = 0; t < TK / 128; t++) {
      const int g = sj + 32 * t;
      float4 e4 = *(const float4*)&sc[sr * TK + ((g ^ srsw) << 2)];
      e4.x *= inv; e4.y *= inv; e4.z *= inv; e4.w *= inv;
      *(float4*)&att_out[orow + g * 4] = e4;
    }
  }

  // ---- phase 4: O = P @ V ------------------------------------------------
  f32x4 oa0 = {}, oa1 = {};
  const float* pr = sc + l15 * TK;
  const int psw = l15 & 7;
  const size_t vb0 = (((size_t)(b * 8 + h)) * 32 + l15) * TK;
#pragma unroll
  for (int kc = w * (TK / 8); kc < (w + 1) * (TK / 8); kc += 32) {
    const int g0 = (kc >> 2) + l4 * 2;
    float4 p0 = *(const float4*)(pr + ((g0 ^ psw) << 2));
    float4 p1 = *(const float4*)(pr + (((g0 + 1) ^ psw) << 2));
    float f[8] = {p0.x, p0.y, p0.z, p0.w, p1.x, p1.y, p1.z, p1.w};
    uint4v uh, ul;
#pragma unroll
    for (int i = 0; i < 4; i++) {
      unsigned short h0, l0, h1, l1;
      split2(f[2 * i], h0, l0); split2(f[2 * i + 1], h1, l1);
      uh[i] = (unsigned)h0 | ((unsigned)h1 << 16);
      ul[i] = (unsigned)l0 | ((unsigned)l1 << 16);
    }
    bfrag ph = __builtin_bit_cast(bfrag, uh);
    bfrag pl = __builtin_bit_cast(bfrag, ul);
    const size_t vk = vb0 + kc + l4 * 8;
    bfrag v0h = *(const bfrag*)(Vth + vk);
    bfrag v0l = *(const bfrag*)(Vtl + vk);
    bfrag v1h = *(const bfrag*)(Vth + vk + (size_t)16 * TK);
    bfrag v1l = *(const bfrag*)(Vtl + vk + (size_t)16 * TK);
    oa0 = __builtin_amdgcn_mfma_f32_16x16x32_bf16(ph, v0h, oa0, 0, 0, 0);
    oa0 = __builtin_amdgcn_mfma_f32_16x16x32_bf16(ph, v0l, oa0, 0, 0, 0);
    oa0 = __builtin_amdgcn_mfma_f32_16x16x32_bf16(pl, v0h, oa0, 0, 0, 0);
    oa1 = __builtin_amdgcn_mfma_f32_16x16x32_bf16(ph, v1h, oa1, 0, 0, 0);
    oa1 = __builtin_amdgcn_mfma_f32_16x16x32_bf16(ph, v1l, oa1, 0, 0, 0);
    oa1 = __builtin_amdgcn_mfma_f32_16x16x32_bf16(pl, v1h, oa1, 0, 0, 0);
  }
  __syncthreads();               // all reads of sc (P) complete
  float* obuf = sc;              // alias: [8][16] rows x 33-stride partial O
#pragma unroll
  for (int r = 0; r < 4; r++) {
    obuf[(w * 16 + l4 * 4 + r) * 33 + l15]      = oa0[r];
    obuf[(w * 16 + l4 * 4 + r) * 33 + 16 + l15] = oa1[r];
  }
  __syncthreads();
  {
    float s0 = 0.f;
#pragma unroll
    for (int ww = 0; ww < 8; ww++)
      s0 += obuf[(ww * 16 + sr) * 33 + sj];
    s0 *= inv;
    unsigned short h0, l0;
    split2(s0, h0, l0);
    const size_t ob = (((size_t)b * 512 + q0 + sr) * 8 + h) * 32 + sj;
    Oh[ob] = (short)h0;  Ol[ob] = (short)l0;
  }
}

// ---------------- norm-softmax pooling stage 1 ----------------------------
__global__ __launch_bounds__(256) void pool1(
    const float* __restrict__ x, const float* __restrict__ nrm,
    float* __restrict__ partial)
{
  __shared__ float w[512];
  __shared__ float red[4];
  const int b = blockIdx.x, cchunk = blockIdx.y, tid = threadIdx.x;
  float n0 = nrm[b * 512 + tid], n1 = nrm[b * 512 + 256 + tid];
  float lm = fmaxf(n0, n1);
  for (int off = 32; off > 0; off >>= 1) lm = fmaxf(lm, __shfl_xor(lm, off, 64));
  if ((tid & 63) == 0) red[tid >> 6] = lm;
  __syncthreads();
  float m = fmaxf(fmaxf(red[0], red[1]), fmaxf(red[2], red[3]));
  float e0 = __expf(n0 - m), e1 = __expf(n1 - m);
  float ls = e0 + e1;
  for (int off = 32; off > 0; off >>= 1) ls += __shfl_xor(ls, off, 64);
  __syncthreads();
  if ((tid & 63) == 0) red[tid >> 6] = ls;
  __syncthreads();
  float inv = 1.f / (red[0] + red[1] + red[2] + red[3]);
  w[tid] = e0 * inv; w[tid + 256] = e1 * inv;
  __syncthreads();
  float acc = 0.f;
  const int t0 = cchunk * 128;
  for (int t = t0; t < t0 + 128; t++)
    acc += w[t] * x[((size_t)b * 512 + t) * 256 + tid];
  partial[((size_t)b * 4 + cchunk) * 256 + tid] = acc;
}

// ---------------- pool reduce + FC head (fused) ---------------------------
__global__ __launch_bounds__(256) void pool2fc(
    const float* __restrict__ partial, float* __restrict__ pooled_out,
    const float* __restrict__ fc1_w, const float* __restrict__ fc1_b,
    const float* __restrict__ fc2_w, const float* __restrict__ fc2_b,
    float* __restrict__ label_out)
{
  __shared__ float pl[256];
  __shared__ float hid[256];
  const int b = blockIdx.x, tid = threadIdx.x;
  float s = partial[((size_t)b * 4 + 0) * 256 + tid]
          + partial[((size_t)b * 4 + 1) * 256 + tid]
          + partial[((size_t)b * 4 + 2) * 256 + tid]
          + partial[((size_t)b * 4 + 3) * 256 + tid];
  pooled_out[b * 256 + tid] = s;
  pl[tid] = s;
  __syncthreads();
  float acc = fc1_b[tid];
  for (int k = 0; k < 256; k++)
    acc += pl[k] * fc1_w[k * 256 + tid];
  hid[tid] = fmaxf(acc, 0.f);
  __syncthreads();
  if (tid < 2) {
    float s2 = fc2_b[tid];
    for (int k = 0; k < 256; k++)
      s2 += hid[k] * fc2_w[k * 2 + tid];
    label_out[b * 2 + tid] = s2;
  }
}

extern "C" void kernel_launch(void* const* d_in, const int* in_sizes, int n_in,
                              void* d_out, int out_size, void* d_ws, size_t ws_size,
                              hipStream_t stream)
{
  const float* trg   = (const float*)d_in[0];
  const float* src   = (const float*)d_in[1];
  const float* ft_w  = (const float*)d_in[2];
  const float* ft_b  = (const float*)d_in[3];
  const float* fc1_w = (const float*)d_in[4];
  const float* fc1_b = (const float*)d_in[5];
  const float* fc2_w = (const float*)d_in[6];
  const float* fc2_b = (const float*)d_in[7];
  const float* ln_g  = (const float*)d_in[8];
  const float* ln_b  = (const float*)d_in[9];
  const float* pf_w1 = (const float*)d_in[10];
  const float* pf_b1 = (const float*)d_in[11];
  const float* pf_w2 = (const float*)d_in[12];
  const float* pf_b2 = (const float*)d_in[13];
  const float* aw[2][8];
  for (int p = 0; p < 2; p++)
    for (int i = 0; i < 8; i++) aw[p][i] = (const float*)d_in[14 + p * 8 + i];
  float* outp = (float*)d_out;

  char* wsb = (char*)d_ws;
  const size_t MB = 1u << 20;
  float* x     = (float*)(wsb);
  short* x_hi  = (short*)(wsb + 8 * MB);
  short* x_lo  = (short*)(wsb + 12 * MB);
  short* qbh   = (short*)(wsb + 16 * MB);
  short* qbl   = (short*)(wsb + 20 * MB);
  short* sakh  = (short*)(wsb + 24 * MB);
  short* sakl  = (short*)(wsb + 28 * MB);
  short* savth = (short*)(wsb + 32 * MB);
  short* savtl = (short*)(wsb + 36 * MB);
  short* obh   = (short*)(wsb + 40 * MB);
  short* obl   = (short*)(wsb + 44 * MB);
  short* srch  = (short*)(wsb + 48 * MB);
  short* srcl  = (short*)(wsb + 56 * MB);
  short* eakh[2]  = {(short*)(wsb + 64 * MB),  (short*)(wsb + 96 * MB)};
  short* eakl[2]  = {(short*)(wsb + 72 * MB),  (short*)(wsb + 104 * MB)};
  short* eavth[2] = {(short*)(wsb + 80 * MB),  (short*)(wsb + 112 * MB)};
  short* eavtl[2] = {(short*)(wsb + 88 * MB),  (short*)(wsb + 120 * MB)};
  short* ffmh  = (short*)(wsb + 128 * MB);
  short* ffml  = (short*)(wsb + 136 * MB);
  short* w_hi  = (short*)(wsb + 144 * MB);
  short* w_lo  = (short*)(wsb + 148 * MB);
  // aliases (disjoint lifetimes):
  short* trgh = ffmh;                // pre-loop only
  short* trgl = ffml;
  float* nrm  = (float*)qbh;         // post-loop (32KB)
  float* part = (float*)qbh + 8192;  // post-loop (64KB)

  // weight layout (elems): ftT@0; eakv@16384 (l0k,l0v,l1k,l1v x65536);
  // per-layer Lb = 278528 + l*655360: saQKV@0(196608) saO@196608 eaQ@262144
  // eaO@327680 pf1T@393216(131072) pf2T@524288(131072)
  auto Lb = [](int l) -> size_t { return 278528 + (size_t)l * 655360; };

  {  // ---- one-time prep: split all weights (one launch) ----
    WAll P{};
    int t = 0, e = 0;
    auto add = [&](const float* s, int K, int N, size_t dst) {
      P.d[e].src = s; P.d[e].dst = (long long)dst;
      P.d[e].K = K; P.d[e].N = N; P.d[e].tile0 = t;
      t += (K / 32) * (N / 32); e++;
    };
    add(ft_w, 64, 256, 0);
    add(aw[1][2], 256, 256, 16384);            // l0 EA wk
    add(aw[1][4], 256, 256, 81920);            // l0 EA wv
    add(aw[1][2] + 65536, 256, 256, 147456);   // l1 EA wk
    add(aw[1][4] + 65536, 256, 256, 212992);   // l1 EA wv
    for (int l = 0; l < 2; l++) {
      const size_t wo = (size_t)l * 65536;
      add(aw[0][0] + wo, 256, 256, Lb(l));               // SA wq
      add(aw[0][2] + wo, 256, 256, Lb(l) + 65536);       // SA wk
      add(aw[0][4] + wo, 256, 256, Lb(l) + 131072);      // SA wv
      add(aw[0][6] + wo, 256, 256, Lb(l) + 196608);      // SA wo
      add(aw[1][0] + wo, 256, 256, Lb(l) + 262144);      // EA wq
      add(aw[1][6] + wo, 256, 256, Lb(l) + 327680);      // EA wo
      add(pf_w1 + (size_t)l * 131072, 256, 512, Lb(l) + 393216);
      add(pf_w2 + (size_t)l * 131072, 512, 256, Lb(l) + 524288);
    }
    wsplit_all<<<t, 256, 0, stream>>>(P, w_hi, w_lo);
  }
  xsplit<<<512, 256, 0, stream>>>(trg, trgh, trgl, 131072);
  xsplit<<<4096, 256, 0, stream>>>(src, srch, srcl, 1048576);

  // EA K/V for both layers (src-only dependency), one launch
  gemm_eakv<<<dim3(128, 8), 256, 0, stream>>>(
      srch, srcl, w_hi + 16384, w_lo + 16384,
      aw[1][3], aw[1][5], aw[1][3] + 256, aw[1][5] + 256,
      eakh[0], eakl[0], eavth[0], eavtl[0],
      eakh[1], eakl[1], eavth[1], eavtl[1], 16384, 256);

  // feature transform: x = trg @ ft_w + ft_b (emits x fp32 + hi/lo)
  gemm_mfma<false, true, true><<<dim3(64, 2), 256, 0, stream>>>(
      trgh, trgl, w_hi, w_lo, ft_b, x, x_hi, x_lo, 8192, 256, 64);

  for (int l = 0; l < 2; l++) {
    const size_t bo = (size_t)l * 256;
    // ---- self attention ----
    gemm_qkv<<<dim3(64, 6), 256, 0, stream>>>(
        x_hi, x_lo, w_hi + Lb(l), w_lo + Lb(l),
        aw[0][1] + bo, aw[0][3] + bo, aw[0][5] + bo,
        qbh, qbl, sakh, sakl, savth, savtl, 8192, 256, 9);
    attn_mfma<512><<<4096, 512, 0, stream>>>(
        qbh, qbl, sakh, sakl, savth, savtl, obh, obl, (float*)nullptr);
    gemm_oln<false><<<128, 256, 0, stream>>>(
        obh, obl, w_hi + Lb(l) + 196608, w_lo + Lb(l) + 196608,
        aw[0][7] + bo, ln_g + bo, ln_b + bo, x, x_hi, x_lo, nullptr, 256);
    // ---- encoder (cross) attention ----
    gemm_mfma<false, true, false><<<dim3(64, 2), 256, 0, stream>>>(
        x_hi, x_lo, w_hi + Lb(l) + 262144, w_lo + Lb(l) + 262144,
        aw[1][1] + bo, nullptr, qbh, qbl, 8192, 256, 256);
    {
      float* att = (l == 1) ? (outp + 4128) : (float*)nullptr;
      attn_mfma<1024><<<4096, 512, 0, stream>>>(
          qbh, qbl, eakh[l], eakl[l], eavth[l], eavtl[l], obh, obl, att);
    }
    gemm_oln<false><<<128, 256, 0, stream>>>(
        obh, obl, w_hi + Lb(l) + 327680, w_lo + Lb(l) + 327680,
        aw[1][7] + bo, ln_g + bo, ln_b + bo, x, x_hi, x_lo, nullptr, 256);
    // ---- feed forward ----
    gemm_mfma<true, true, false><<<dim3(64, 4), 256, 0, stream>>>(
        x_hi, x_lo, w_hi + Lb(l) + 393216, w_lo + Lb(l) + 393216,
        pf_b1 + (size_t)l * 512, nullptr, ffmh, ffml, 8192, 512, 256);
    if (l == 0) {
      gemm_oln<false><<<128, 256, 0, stream>>>(
          ffmh, ffml, w_hi + Lb(l) + 524288, w_lo + Lb(l) + 524288,
          pf_b2 + bo, ln_g + bo, ln_b + bo, x, x_hi, x_lo, nullptr, 512);
    } else {
      gemm_oln<true><<<128, 256, 0, stream>>>(
          ffmh, ffml, w_hi + Lb(l) + 524288, w_lo + Lb(l) + 524288,
          pf_b2 + bo, ln_g + bo, ln_b + bo, x, x_hi, x_lo, nrm, 512);
    }
  }

  // ---- pooling + head ----
  pool1<<<dim3(16, 4), 256, 0, stream>>>(x, nrm, part);
  pool2fc<<<16, 256, 0, stream>>>(part, outp + 32, fc1_w, fc1_b,
                                  fc2_w, fc2_b, outp);
}